// Round 15
// baseline (135.074 us; speedup 1.0000x reference)
//
#include <hip/hip_runtime.h>
#include <hip/hip_fp16.h>
#include <cfloat>
#include <cmath>

#define HW 25600      // 160*160
#define WIDTH 160
#define NB 4
#define NC 128

typedef float f32x2 __attribute__((ext_vector_type(2)));

__device__ __forceinline__ float gelu_exact(float x) {
    return 0.5f * x * (1.f + erff(x * 0.70710678118654752f));
}
__device__ __forceinline__ float sigmoidf_(float x) {
    return 1.f / (1.f + expf(-x));
}

__device__ __forceinline__ unsigned pack_pkrtz(float a, float b) {
    return __builtin_bit_cast(unsigned, __builtin_amdgcn_cvt_pkrtz(a, b));
}
__device__ __forceinline__ __half2 u2h(unsigned u) {
    return __builtin_bit_cast(__half2, u);
}
__device__ __forceinline__ float h2sum(__half2 h) {
    return __half2float(__low2half(h)) + __half2float(__high2half(h));
}

// ---------------- K1: per-plane means + (merged) conv-weight pack ----------------
__global__ __launch_bounds__(256) void mean_pack_kernel(const float* __restrict__ RGB,
                                                        const float* __restrict__ T,
                                                        const float* __restrict__ dww,
                                                        float* __restrict__ means,
                                                        unsigned* __restrict__ wpk) {
    int p = blockIdx.x;
    if (p >= 1024) {
        int i = (p - 1024) * 256 + threadIdx.x;  // 128*98 = 12544
        if (i < 128 * 98) {
            int g = i / 98; int r = i - g * 98;
            int ky = r / 14; int r2 = r - ky * 14;
            int oc = r2 / 7; int kx = r2 - oc * 7;
            int o = 2 * g + oc;
            float wa = dww[(o * 2 + 0) * 49 + ky * 7 + kx];
            float wb = dww[(o * 2 + 1) * 49 + ky * 7 + kx];
            wpk[i] = pack_pkrtz(wa, wb);
        }
        return;
    }
    const float* src = (p < 512) ? (RGB + (size_t)p * HW)
                                 : (T + (size_t)(p - 512) * HW);
    const float4* s4 = (const float4*)src;
    float s = 0.f;
    for (int i = threadIdx.x; i < HW / 4; i += 256) {
        float4 v = s4[i];
        s += (v.x + v.y) + (v.z + v.w);
    }
    for (int off = 32; off; off >>= 1) s += __shfl_down(s, off);
    __shared__ float r[4];
    if ((threadIdx.x & 63) == 0) r[threadIdx.x >> 6] = s;
    __syncthreads();
    if (threadIdx.x == 0) means[p] = (r[0] + r[1] + r[2] + r[3]) * (1.f / (float)HW);
}

// ---------------- K2: feature-pool MLP + L2-normalize, per (tau,b) ----------------
__global__ __launch_bounds__(256) void mlp_kernel(const float* __restrict__ means,
                                                  const float* __restrict__ dww,
                                                  const float* __restrict__ dwb,
                                                  const float* __restrict__ uww,
                                                  const float* __restrict__ uwb,
                                                  float* __restrict__ ynorm) {
    int tb = blockIdx.x;  // tau*4 + b
    int t = threadIdx.x;
    __shared__ float sm[128];
    __shared__ float sh[256];
    __shared__ float zz[256];
    __shared__ float r4[4];
    if (t < 128) sm[t] = means[tb * 128 + t];
    __syncthreads();
    float a = dwb[t];
    const float* wrow = dww + t * 128;
    for (int c = 0; c < 128; ++c) a += wrow[c] * sm[c];
    sh[t] = gelu_exact(a);
    __syncthreads();
    int c = t & 127, half = t >> 7;
    float z = 0.f;
    const float* urow = uww + c * 256 + half * 128;
    const float* hh = sh + half * 128;
    for (int j = 0; j < 128; ++j) z += urow[j] * hh[j];
    zz[t] = z;
    __syncthreads();
    float y = 0.f;
    if (t < 128) y = zz[t] + zz[t + 128] + uwb[t];
    float p = y * y;
    for (int off = 32; off; off >>= 1) p += __shfl_down(p, off);
    if ((t & 63) == 0) r4[t >> 6] = p;
    __syncthreads();
    float nrm = sqrtf(r4[0] + r4[1] + r4[2] + r4[3]);
    if (t < 128) ynorm[tb * 128 + t] = y / nrm;
}

// ---------------- K3: gated grouped 7x7 conv + spatial max ----------------
// R15: ONE asm barrier holding ALL 20 accumulators "+v" per ky iteration --
// forces simultaneous liveness, making the compiler's one-output-at-a-time
// refission (VGPR=20, redundant LDS re-reads, 67us plateau) illegal.
#define TW2 166
#define THR 22
#define NYT 10
__global__ __launch_bounds__(256, 4) void conv_max_kernel(const float* __restrict__ RGB,
                                                          const float* __restrict__ T,
                                                          const unsigned* __restrict__ wpk,
                                                          const float* __restrict__ ynorm,
                                                          float* __restrict__ part) {
    // bijective XCD swizzle: 5120 blocks, 5120 % 8 == 0
    int orig = blockIdx.x;
    int wg = (orig & 7) * 640 + (orig >> 3);
    int b  = wg / 1280;
    int rr = wg - b * 1280;
    int g  = rr / NYT;
    int yt = rr - g * NYT;
    int t  = threadIdx.x;
    __shared__ unsigned tile[THR * TW2];   // 14.6 KB
    __shared__ float r0s[4], r1s[4];
    int ic0 = 2 * g;
    int c0 = ic0 & 127, c1 = (ic0 + 1) & 127;
    const float* base = (ic0 < 128) ? RGB : T;
    const float* plane0 = base + ((size_t)(b * 128 + c0)) * HW;
    const float* plane1 = base + ((size_t)(b * 128 + c1)) * HW;
    int i0 = b * 128 + c0, i1 = b * 128 + c1;
    int j0 = i0 & 3, k0 = i0 >> 2, j1 = i1 & 3, k1 = i1 >> 2;
    float gate0 = sigmoidf_(128.f * ynorm[j0 * 128 + j0] * ynorm[512 + j0 * 128 + k0]);
    float gate1 = sigmoidf_(128.f * ynorm[j1 * 128 + j1] * ynorm[512 + j1 * 128 + k1]);
    int y0 = yt * 16 - 3;
    for (int e = t; e < THR * TW2; e += 256) {
        int row = e / TW2;
        int col = e - row * TW2;
        int gy = y0 + row, gx = col - 3;
        float v0 = 0.f, v1 = 0.f;
        if (gy >= 0 && gy < 160 && gx >= 0 && gx < 160) {
            int off = gy * WIDTH + gx;
            v0 = plane0[off] * gate0;
            v1 = plane1[off] * gate1;
        }
        tile[e] = pack_pkrtz(v0, v1);
    }
    __syncthreads();
    int xs = (t & 15) * 10;     // 40 B aligned -> uint2 ok
    int ys = t >> 4;            // 0..15
    unsigned uA0 = 0u, uA1 = 0u, uA2 = 0u, uA3 = 0u, uA4 = 0u;
    unsigned uA5 = 0u, uA6 = 0u, uA7 = 0u, uA8 = 0u, uA9 = 0u;
    unsigned uB0 = 0u, uB1 = 0u, uB2 = 0u, uB3 = 0u, uB4 = 0u;
    unsigned uB5 = 0u, uB6 = 0u, uB7 = 0u, uB8 = 0u, uB9 = 0u;
    const unsigned* wgp = wpk + g * 98;   // block-uniform -> scalar loads
    #pragma unroll
    for (int ky = 0; ky < 7; ++ky) {
        // ALL 20 accumulators live at this point, every iteration:
        asm volatile("" : "+v"(uA0), "+v"(uA1), "+v"(uA2), "+v"(uA3), "+v"(uA4),
                          "+v"(uA5), "+v"(uA6), "+v"(uA7), "+v"(uA8), "+v"(uA9),
                          "+v"(uB0), "+v"(uB1), "+v"(uB2), "+v"(uB3), "+v"(uB4),
                          "+v"(uB5), "+v"(uB6), "+v"(uB7), "+v"(uB8), "+v"(uB9));
        __half2 A0 = u2h(uA0), A1 = u2h(uA1), A2 = u2h(uA2), A3 = u2h(uA3), A4 = u2h(uA4);
        __half2 A5 = u2h(uA5), A6 = u2h(uA6), A7 = u2h(uA7), A8 = u2h(uA8), A9 = u2h(uA9);
        __half2 B0 = u2h(uB0), B1 = u2h(uB1), B2 = u2h(uB2), B3 = u2h(uB3), B4 = u2h(uB4);
        __half2 B5 = u2h(uB5), B6 = u2h(uB6), B7 = u2h(uB7), B8 = u2h(uB8), B9 = u2h(uB9);
        unsigned wk[14];
        #pragma unroll
        for (int j = 0; j < 14; ++j) wk[j] = wgp[ky * 14 + j];
        const uint2* tr2 = (const uint2*)(tile + (ys + ky) * TW2 + xs);
        unsigned win[16];
        #pragma unroll
        for (int j = 0; j < 8; ++j) {
            uint2 p = tr2[j];
            win[2 * j] = p.x;
            win[2 * j + 1] = p.y;
        }
        #pragma unroll
        for (int kx = 0; kx < 7; ++kx) {
            __half2 w0 = u2h(wk[kx]);
            __half2 w1 = u2h(wk[7 + kx]);
            __half2 v;
            v = u2h(win[kx + 0]); A0 = __hfma2(w0, v, A0); B0 = __hfma2(w1, v, B0);
            v = u2h(win[kx + 1]); A1 = __hfma2(w0, v, A1); B1 = __hfma2(w1, v, B1);
            v = u2h(win[kx + 2]); A2 = __hfma2(w0, v, A2); B2 = __hfma2(w1, v, B2);
            v = u2h(win[kx + 3]); A3 = __hfma2(w0, v, A3); B3 = __hfma2(w1, v, B3);
            v = u2h(win[kx + 4]); A4 = __hfma2(w0, v, A4); B4 = __hfma2(w1, v, B4);
            v = u2h(win[kx + 5]); A5 = __hfma2(w0, v, A5); B5 = __hfma2(w1, v, B5);
            v = u2h(win[kx + 6]); A6 = __hfma2(w0, v, A6); B6 = __hfma2(w1, v, B6);
            v = u2h(win[kx + 7]); A7 = __hfma2(w0, v, A7); B7 = __hfma2(w1, v, B7);
            v = u2h(win[kx + 8]); A8 = __hfma2(w0, v, A8); B8 = __hfma2(w1, v, B8);
            v = u2h(win[kx + 9]); A9 = __hfma2(w0, v, A9); B9 = __hfma2(w1, v, B9);
        }
        uA0 = __builtin_bit_cast(unsigned, A0); uA1 = __builtin_bit_cast(unsigned, A1);
        uA2 = __builtin_bit_cast(unsigned, A2); uA3 = __builtin_bit_cast(unsigned, A3);
        uA4 = __builtin_bit_cast(unsigned, A4); uA5 = __builtin_bit_cast(unsigned, A5);
        uA6 = __builtin_bit_cast(unsigned, A6); uA7 = __builtin_bit_cast(unsigned, A7);
        uA8 = __builtin_bit_cast(unsigned, A8); uA9 = __builtin_bit_cast(unsigned, A9);
        uB0 = __builtin_bit_cast(unsigned, B0); uB1 = __builtin_bit_cast(unsigned, B1);
        uB2 = __builtin_bit_cast(unsigned, B2); uB3 = __builtin_bit_cast(unsigned, B3);
        uB4 = __builtin_bit_cast(unsigned, B4); uB5 = __builtin_bit_cast(unsigned, B5);
        uB6 = __builtin_bit_cast(unsigned, B6); uB7 = __builtin_bit_cast(unsigned, B7);
        uB8 = __builtin_bit_cast(unsigned, B8); uB9 = __builtin_bit_cast(unsigned, B9);
    }
    {
        __half2 A0 = u2h(uA0), A1 = u2h(uA1), A2 = u2h(uA2), A3 = u2h(uA3), A4 = u2h(uA4);
        __half2 A5 = u2h(uA5), A6 = u2h(uA6), A7 = u2h(uA7), A8 = u2h(uA8), A9 = u2h(uA9);
        __half2 B0 = u2h(uB0), B1 = u2h(uB1), B2 = u2h(uB2), B3 = u2h(uB3), B4 = u2h(uB4);
        __half2 B5 = u2h(uB5), B6 = u2h(uB6), B7 = u2h(uB7), B8 = u2h(uB8), B9 = u2h(uB9);
        float m0 = fmaxf(fmaxf(fmaxf(h2sum(A0), h2sum(A1)), fmaxf(h2sum(A2), h2sum(A3))),
                         fmaxf(fmaxf(h2sum(A4), h2sum(A5)),
                               fmaxf(fmaxf(h2sum(A6), h2sum(A7)), fmaxf(h2sum(A8), h2sum(A9)))));
        float m1 = fmaxf(fmaxf(fmaxf(h2sum(B0), h2sum(B1)), fmaxf(h2sum(B2), h2sum(B3))),
                         fmaxf(fmaxf(h2sum(B4), h2sum(B5)),
                               fmaxf(fmaxf(h2sum(B6), h2sum(B7)), fmaxf(h2sum(B8), h2sum(B9)))));
        for (int off = 32; off; off >>= 1) {
            m0 = fmaxf(m0, __shfl_down(m0, off));
            m1 = fmaxf(m1, __shfl_down(m1, off));
        }
        if ((t & 63) == 0) { r0s[t >> 6] = m0; r1s[t >> 6] = m1; }
        __syncthreads();
        if (t == 0) {
            m0 = fmaxf(fmaxf(r0s[0], r0s[1]), fmaxf(r0s[2], r0s[3]));
            m1 = fmaxf(fmaxf(r1s[0], r1s[1]), fmaxf(r1s[2], r1s[3]));
            int bb = ((b * 128 + g) * NYT + yt) * 2;
            part[bb] = m0;
            part[bb + 1] = m1;
        }
    }
}

// ---------------- K4: max-reduce + channel-att MLP -> per-channel coefficients ----------------
__global__ __launch_bounds__(256) void att_kernel(const float* __restrict__ ynorm,
                                                  const float* __restrict__ part,
                                                  const float* __restrict__ dwb,
                                                  const float* __restrict__ cdw,
                                                  const float* __restrict__ cdb,
                                                  const float* __restrict__ cuw,
                                                  const float* __restrict__ cub,
                                                  const float* __restrict__ srw,
                                                  const float* __restrict__ stw,
                                                  float* __restrict__ coefs) {
    int t = threadIdx.x;
    __shared__ float scg[512];
    __shared__ float smax[1024];
    __shared__ float sh2[64];
    __shared__ float sfg[1024];
    for (int idx = t; idx < 512; idx += 256) {
        int kk = idx >> 2, j = idx & 3;
        scg[idx] = sigmoidf_(128.f * ynorm[j * 128 + j] * ynorm[512 + j * 128 + kk]);
    }
    for (int idx = t; idx < 1024; idx += 256) {
        int b = idx >> 8, o = idx & 255;
        int gg = o >> 1, oc = o & 1;
        const float* pp = part + ((b * 128 + gg) * NYT) * 2 + oc;
        float m = pp[0];
        #pragma unroll
        for (int yt = 1; yt < NYT; ++yt) m = fmaxf(m, pp[yt * 2]);
        smax[idx] = m + dwb[o];
    }
    __syncthreads();
    if (t < 64) {
        int b = t >> 4, j = t & 15;
        float a = cdb[j];
        const float* wrow = cdw + j * 256;
        const float* mx = smax + b * 256;
        for (int o = 0; o < 256; ++o) a += wrow[o] * mx[o];
        sh2[t] = gelu_exact(a);
    }
    __syncthreads();
    for (int idx = t; idx < 1024; idx += 256) {
        int b = idx >> 8, o = idx & 255;
        float z = cub[o];
        const float* ur = cuw + o * 16;
        const float* hh = sh2 + b * 16;
        #pragma unroll
        for (int j = 0; j < 16; ++j) z += ur[j] * hh[j];
        sfg[idx] = sigmoidf_(z);
    }
    __syncthreads();
    for (int idx = t; idx < 512; idx += 256) {
        int b = idx >> 7, c = idx & 127;
        float cgv = scg[idx];
        float ar = cgv * sfg[b * 256 + c] + 1.f - cgv;
        float at = cgv * sfg[b * 256 + 128 + c] + 1.f - cgv;
        coefs[idx] = ar;
        coefs[512 + idx] = at;
        coefs[1024 + idx] = ar * srw[c];
        coefs[1536 + idx] = at * stw[c];
    }
}

// ---------------- K5: spatial-att fuse, single pass, float2, 8 warps x 16ch ----------------
__global__ __launch_bounds__(512, 4) void fuse_kernel(const float* __restrict__ RGB,
                                                      const float* __restrict__ T,
                                                      const float* __restrict__ coefs,
                                                      const float* __restrict__ srb,
                                                      const float* __restrict__ stb,
                                                      float* __restrict__ out) {
    int b = blockIdx.y;
    int t = threadIdx.x;
    int w = t >> 6, lane = t & 63;
    int pix = blockIdx.x * 128 + lane * 2;
    __shared__ float sco[4][128];
    if (t < 512) {
        int a = t >> 7, c = t & 127;
        sco[a][c] = coefs[a * 512 + b * 128 + c];
    }
    __syncthreads();
    const float* rp = RGB + (size_t)b * NC * HW;
    const float* tp = T + (size_t)b * NC * HW;
    f32x2 rv[16], tv[16];
    f32x2 df; df.x = 0.f; df.y = 0.f;
    #pragma unroll
    for (int ci = 0; ci < 16; ++ci) {
        int c = w * 16 + ci;
        size_t off = (size_t)c * HW + pix;
        rv[ci] = *(const f32x2*)(rp + off);
        tv[ci] = *(const f32x2*)(tp + off);
        float wrc = sco[2][c], wtc = sco[3][c];
        df.x += rv[ci].x * wrc - tv[ci].x * wtc;
        df.y += rv[ci].y * wrc - tv[ci].y * wtc;
    }
    __shared__ f32x2 sdf[8][64];
    sdf[w][lane] = df;
    __syncthreads();
    float sx = srb[0] - stb[0], sy = sx;
    #pragma unroll
    for (int ww = 0; ww < 8; ++ww) {
        f32x2 d = sdf[ww][lane];
        sx += d.x;
        sy += d.y;
    }
    float ax = sigmoidf_(sx), ay = sigmoidf_(sy);
    float* outR = out + (size_t)b * NC * HW;
    float* outT = out + (size_t)NB * NC * HW + (size_t)b * NC * HW;
    #pragma unroll
    for (int ci = 0; ci < 16; ++ci) {
        int c = w * 16 + ci;
        size_t off = (size_t)c * HW + pix;
        float arc = sco[0][c], atc = sco[1][c];
        f32x2 o1, o2;
        o1.x = rv[ci].x * arc * ax;         o1.y = rv[ci].y * arc * ay;
        o2.x = tv[ci].x * atc * (1.f - ax); o2.y = tv[ci].y * atc * (1.f - ay);
        __builtin_nontemporal_store(o1, (f32x2*)(outR + off));
        __builtin_nontemporal_store(o2, (f32x2*)(outT + off));
    }
}

extern "C" void kernel_launch(void* const* d_in, const int* in_sizes, int n_in,
                              void* d_out, int out_size, void* d_ws, size_t ws_size,
                              hipStream_t stream) {
    const float* RGB       = (const float*)d_in[0];
    const float* T         = (const float*)d_in[1];
    const float* fp_down_w = (const float*)d_in[2];
    const float* fp_down_b = (const float*)d_in[3];
    const float* fp_up_w   = (const float*)d_in[4];
    const float* fp_up_b   = (const float*)d_in[5];
    const float* dw_w      = (const float*)d_in[6];
    const float* dw_b      = (const float*)d_in[7];
    const float* ca_down_w = (const float*)d_in[8];
    const float* ca_down_b = (const float*)d_in[9];
    const float* ca_up_w   = (const float*)d_in[10];
    const float* ca_up_b   = (const float*)d_in[11];
    const float* sr_w      = (const float*)d_in[12];
    const float* sr_b      = (const float*)d_in[13];
    const float* st_w      = (const float*)d_in[14];
    const float* st_b      = (const float*)d_in[15];
    float* out = (float*)d_out;
    float* ws  = (float*)d_ws;

    // ws float layout (proven footprint):
    //   [0,1024)        means
    //   [1024,2048)     ynorm
    //   [2048,12288)    conv partial maxes
    //   [12288,14336)   coefs: alpha_r | alpha_t | wr | wt
    //   [14336,26880)   wpk: packed f16x2 conv weights [g][ky][oc][kx]
    unsigned* wpk = (unsigned*)(ws + 14336);
    mean_pack_kernel<<<1073, 256, 0, stream>>>(RGB, T, dw_w, ws, wpk);
    mlp_kernel<<<8, 256, 0, stream>>>(ws, fp_down_w, fp_down_b, fp_up_w, fp_up_b, ws + 1024);
    conv_max_kernel<<<5120, 256, 0, stream>>>(RGB, T, wpk, ws + 1024, ws + 2048);
    att_kernel<<<1, 256, 0, stream>>>(ws + 1024, ws + 2048, dw_b, ca_down_w, ca_down_b,
                                      ca_up_w, ca_up_b, sr_w, st_w, ws + 12288);
    fuse_kernel<<<dim3(200, 4), 512, 0, stream>>>(RGB, T, ws + 12288, sr_b, st_b, out);
}

// Round 16
// 134.042 us; speedup vs baseline: 1.0077x; 1.0077x over previous
//
#include <hip/hip_runtime.h>
#include <cfloat>
#include <cmath>

#define HW 25600      // 160*160
#define WIDTH 160
#define NB 4
#define NC 128

typedef float f32x2 __attribute__((ext_vector_type(2)));
typedef _Float16 h2 __attribute__((ext_vector_type(2)));

__device__ __forceinline__ float gelu_exact(float x) {
    return 0.5f * x * (1.f + erff(x * 0.70710678118654752f));
}
__device__ __forceinline__ float sigmoidf_(float x) {
    return 1.f / (1.f + expf(-x));
}

__device__ __forceinline__ unsigned pack_pkrtz(float a, float b) {
    return __builtin_bit_cast(unsigned, __builtin_amdgcn_cvt_pkrtz(a, b));
}
__device__ __forceinline__ h2 u2h(unsigned u) {
    return __builtin_bit_cast(h2, u);
}
__device__ __forceinline__ float h2sum(h2 h) {
    return (float)h[0] + (float)h[1];
}
// Most direct path to v_pk_fma_f16: llvm.fma.v2f16 on a native clang vector.
// (R16: __hfma2 scalarized to 2x v_fma_f16 -> 1960 scalar MACs = the 67us
// plateau. If this also scalarizes, conv is at its scalar-VALU floor.)
__device__ __forceinline__ h2 fma2h(h2 a, h2 b, h2 c) {
    return __builtin_elementwise_fma(a, b, c);
}

// ---------------- K1: per-plane means + (merged) conv-weight pack ----------------
__global__ __launch_bounds__(256) void mean_pack_kernel(const float* __restrict__ RGB,
                                                        const float* __restrict__ T,
                                                        const float* __restrict__ dww,
                                                        float* __restrict__ means,
                                                        unsigned* __restrict__ wpk) {
    int p = blockIdx.x;
    if (p >= 1024) {
        int i = (p - 1024) * 256 + threadIdx.x;  // 128*98 = 12544
        if (i < 128 * 98) {
            int g = i / 98; int r = i - g * 98;
            int ky = r / 14; int r2 = r - ky * 14;
            int oc = r2 / 7; int kx = r2 - oc * 7;
            int o = 2 * g + oc;
            float wa = dww[(o * 2 + 0) * 49 + ky * 7 + kx];
            float wb = dww[(o * 2 + 1) * 49 + ky * 7 + kx];
            wpk[i] = pack_pkrtz(wa, wb);
        }
        return;
    }
    const float* src = (p < 512) ? (RGB + (size_t)p * HW)
                                 : (T + (size_t)(p - 512) * HW);
    const float4* s4 = (const float4*)src;
    float s = 0.f;
    for (int i = threadIdx.x; i < HW / 4; i += 256) {
        float4 v = s4[i];
        s += (v.x + v.y) + (v.z + v.w);
    }
    for (int off = 32; off; off >>= 1) s += __shfl_down(s, off);
    __shared__ float r[4];
    if ((threadIdx.x & 63) == 0) r[threadIdx.x >> 6] = s;
    __syncthreads();
    if (threadIdx.x == 0) means[p] = (r[0] + r[1] + r[2] + r[3]) * (1.f / (float)HW);
}

// ---------------- K2: feature-pool MLP + L2-normalize, per (tau,b) ----------------
__global__ __launch_bounds__(256) void mlp_kernel(const float* __restrict__ means,
                                                  const float* __restrict__ dww,
                                                  const float* __restrict__ dwb,
                                                  const float* __restrict__ uww,
                                                  const float* __restrict__ uwb,
                                                  float* __restrict__ ynorm) {
    int tb = blockIdx.x;  // tau*4 + b
    int t = threadIdx.x;
    __shared__ float sm[128];
    __shared__ float sh[256];
    __shared__ float zz[256];
    __shared__ float r4[4];
    if (t < 128) sm[t] = means[tb * 128 + t];
    __syncthreads();
    float a = dwb[t];
    const float* wrow = dww + t * 128;
    for (int c = 0; c < 128; ++c) a += wrow[c] * sm[c];
    sh[t] = gelu_exact(a);
    __syncthreads();
    int c = t & 127, half = t >> 7;
    float z = 0.f;
    const float* urow = uww + c * 256 + half * 128;
    const float* hh = sh + half * 128;
    for (int j = 0; j < 128; ++j) z += urow[j] * hh[j];
    zz[t] = z;
    __syncthreads();
    float y = 0.f;
    if (t < 128) y = zz[t] + zz[t + 128] + uwb[t];
    float p = y * y;
    for (int off = 32; off; off >>= 1) p += __shfl_down(p, off);
    if ((t & 63) == 0) r4[t >> 6] = p;
    __syncthreads();
    float nrm = sqrtf(r4[0] + r4[1] + r4[2] + r4[3]);
    if (t < 128) ynorm[tb * 128 + t] = y / nrm;
}

// ---------------- K3: gated grouped 7x7 conv + spatial max ----------------
// R16: native _Float16 vector + __builtin_elementwise_fma (llvm.fma.v2f16).
#define TW2 166
#define THR 22
#define NYT 10
__global__ __launch_bounds__(256, 4) void conv_max_kernel(const float* __restrict__ RGB,
                                                          const float* __restrict__ T,
                                                          const unsigned* __restrict__ wpk,
                                                          const float* __restrict__ ynorm,
                                                          float* __restrict__ part) {
    // bijective XCD swizzle: 5120 blocks, 5120 % 8 == 0
    int orig = blockIdx.x;
    int wg = (orig & 7) * 640 + (orig >> 3);
    int b  = wg / 1280;
    int rr = wg - b * 1280;
    int g  = rr / NYT;
    int yt = rr - g * NYT;
    int t  = threadIdx.x;
    __shared__ unsigned tile[THR * TW2];   // 14.6 KB
    __shared__ float r0s[4], r1s[4];
    int ic0 = 2 * g;
    int c0 = ic0 & 127, c1 = (ic0 + 1) & 127;
    const float* base = (ic0 < 128) ? RGB : T;
    const float* plane0 = base + ((size_t)(b * 128 + c0)) * HW;
    const float* plane1 = base + ((size_t)(b * 128 + c1)) * HW;
    int i0 = b * 128 + c0, i1 = b * 128 + c1;
    int j0 = i0 & 3, k0 = i0 >> 2, j1 = i1 & 3, k1 = i1 >> 2;
    float gate0 = sigmoidf_(128.f * ynorm[j0 * 128 + j0] * ynorm[512 + j0 * 128 + k0]);
    float gate1 = sigmoidf_(128.f * ynorm[j1 * 128 + j1] * ynorm[512 + j1 * 128 + k1]);
    int y0 = yt * 16 - 3;
    for (int e = t; e < THR * TW2; e += 256) {
        int row = e / TW2;
        int col = e - row * TW2;
        int gy = y0 + row, gx = col - 3;
        float v0 = 0.f, v1 = 0.f;
        if (gy >= 0 && gy < 160 && gx >= 0 && gx < 160) {
            int off = gy * WIDTH + gx;
            v0 = plane0[off] * gate0;
            v1 = plane1[off] * gate1;
        }
        tile[e] = pack_pkrtz(v0, v1);
    }
    __syncthreads();
    int xs = (t & 15) * 10;     // 40 B aligned -> uint2 ok
    int ys = t >> 4;            // 0..15
    h2 zz = (h2)0;
    h2 A0 = zz, A1 = zz, A2 = zz, A3 = zz, A4 = zz;
    h2 A5 = zz, A6 = zz, A7 = zz, A8 = zz, A9 = zz;
    h2 B0 = zz, B1 = zz, B2 = zz, B3 = zz, B4 = zz;
    h2 B5 = zz, B6 = zz, B7 = zz, B8 = zz, B9 = zz;
    const unsigned* wgp = wpk + g * 98;   // block-uniform -> scalar loads
    #pragma unroll
    for (int ky = 0; ky < 7; ++ky) {
        unsigned wk[14];
        #pragma unroll
        for (int j = 0; j < 14; ++j) wk[j] = wgp[ky * 14 + j];
        const uint2* tr2 = (const uint2*)(tile + (ys + ky) * TW2 + xs);
        unsigned win[16];
        #pragma unroll
        for (int j = 0; j < 8; ++j) {
            uint2 p = tr2[j];
            win[2 * j] = p.x;
            win[2 * j + 1] = p.y;
        }
        #pragma unroll
        for (int kx = 0; kx < 7; ++kx) {
            h2 w0 = u2h(wk[kx]);
            h2 w1 = u2h(wk[7 + kx]);
            h2 v;
            v = u2h(win[kx + 0]); A0 = fma2h(w0, v, A0); B0 = fma2h(w1, v, B0);
            v = u2h(win[kx + 1]); A1 = fma2h(w0, v, A1); B1 = fma2h(w1, v, B1);
            v = u2h(win[kx + 2]); A2 = fma2h(w0, v, A2); B2 = fma2h(w1, v, B2);
            v = u2h(win[kx + 3]); A3 = fma2h(w0, v, A3); B3 = fma2h(w1, v, B3);
            v = u2h(win[kx + 4]); A4 = fma2h(w0, v, A4); B4 = fma2h(w1, v, B4);
            v = u2h(win[kx + 5]); A5 = fma2h(w0, v, A5); B5 = fma2h(w1, v, B5);
            v = u2h(win[kx + 6]); A6 = fma2h(w0, v, A6); B6 = fma2h(w1, v, B6);
            v = u2h(win[kx + 7]); A7 = fma2h(w0, v, A7); B7 = fma2h(w1, v, B7);
            v = u2h(win[kx + 8]); A8 = fma2h(w0, v, A8); B8 = fma2h(w1, v, B8);
            v = u2h(win[kx + 9]); A9 = fma2h(w0, v, A9); B9 = fma2h(w1, v, B9);
        }
    }
    float m0 = fmaxf(fmaxf(fmaxf(h2sum(A0), h2sum(A1)), fmaxf(h2sum(A2), h2sum(A3))),
                     fmaxf(fmaxf(h2sum(A4), h2sum(A5)),
                           fmaxf(fmaxf(h2sum(A6), h2sum(A7)), fmaxf(h2sum(A8), h2sum(A9)))));
    float m1 = fmaxf(fmaxf(fmaxf(h2sum(B0), h2sum(B1)), fmaxf(h2sum(B2), h2sum(B3))),
                     fmaxf(fmaxf(h2sum(B4), h2sum(B5)),
                           fmaxf(fmaxf(h2sum(B6), h2sum(B7)), fmaxf(h2sum(B8), h2sum(B9)))));
    for (int off = 32; off; off >>= 1) {
        m0 = fmaxf(m0, __shfl_down(m0, off));
        m1 = fmaxf(m1, __shfl_down(m1, off));
    }
    if ((t & 63) == 0) { r0s[t >> 6] = m0; r1s[t >> 6] = m1; }
    __syncthreads();
    if (t == 0) {
        m0 = fmaxf(fmaxf(r0s[0], r0s[1]), fmaxf(r0s[2], r0s[3]));
        m1 = fmaxf(fmaxf(r1s[0], r1s[1]), fmaxf(r1s[2], r1s[3]));
        int bb = ((b * 128 + g) * NYT + yt) * 2;
        part[bb] = m0;
        part[bb + 1] = m1;
    }
}

// ---------------- K4: max-reduce + channel-att MLP -> per-channel coefficients ----------------
__global__ __launch_bounds__(256) void att_kernel(const float* __restrict__ ynorm,
                                                  const float* __restrict__ part,
                                                  const float* __restrict__ dwb,
                                                  const float* __restrict__ cdw,
                                                  const float* __restrict__ cdb,
                                                  const float* __restrict__ cuw,
                                                  const float* __restrict__ cub,
                                                  const float* __restrict__ srw,
                                                  const float* __restrict__ stw,
                                                  float* __restrict__ coefs) {
    int t = threadIdx.x;
    __shared__ float scg[512];
    __shared__ float smax[1024];
    __shared__ float sh2[64];
    __shared__ float sfg[1024];
    for (int idx = t; idx < 512; idx += 256) {
        int kk = idx >> 2, j = idx & 3;
        scg[idx] = sigmoidf_(128.f * ynorm[j * 128 + j] * ynorm[512 + j * 128 + kk]);
    }
    for (int idx = t; idx < 1024; idx += 256) {
        int b = idx >> 8, o = idx & 255;
        int gg = o >> 1, oc = o & 1;
        const float* pp = part + ((b * 128 + gg) * NYT) * 2 + oc;
        float m = pp[0];
        #pragma unroll
        for (int yt = 1; yt < NYT; ++yt) m = fmaxf(m, pp[yt * 2]);
        smax[idx] = m + dwb[o];
    }
    __syncthreads();
    if (t < 64) {
        int b = t >> 4, j = t & 15;
        float a = cdb[j];
        const float* wrow = cdw + j * 256;
        const float* mx = smax + b * 256;
        for (int o = 0; o < 256; ++o) a += wrow[o] * mx[o];
        sh2[t] = gelu_exact(a);
    }
    __syncthreads();
    for (int idx = t; idx < 1024; idx += 256) {
        int b = idx >> 8, o = idx & 255;
        float z = cub[o];
        const float* ur = cuw + o * 16;
        const float* hh = sh2 + b * 16;
        #pragma unroll
        for (int j = 0; j < 16; ++j) z += ur[j] * hh[j];
        sfg[idx] = sigmoidf_(z);
    }
    __syncthreads();
    for (int idx = t; idx < 512; idx += 256) {
        int b = idx >> 7, c = idx & 127;
        float cgv = scg[idx];
        float ar = cgv * sfg[b * 256 + c] + 1.f - cgv;
        float at = cgv * sfg[b * 256 + 128 + c] + 1.f - cgv;
        coefs[idx] = ar;
        coefs[512 + idx] = at;
        coefs[1024 + idx] = ar * srw[c];
        coefs[1536 + idx] = at * stw[c];
    }
}

// ---------------- K5: spatial-att fuse, single pass, float2, 8 warps x 16ch ----------------
__global__ __launch_bounds__(512, 4) void fuse_kernel(const float* __restrict__ RGB,
                                                      const float* __restrict__ T,
                                                      const float* __restrict__ coefs,
                                                      const float* __restrict__ srb,
                                                      const float* __restrict__ stb,
                                                      float* __restrict__ out) {
    int b = blockIdx.y;
    int t = threadIdx.x;
    int w = t >> 6, lane = t & 63;
    int pix = blockIdx.x * 128 + lane * 2;
    __shared__ float sco[4][128];
    if (t < 512) {
        int a = t >> 7, c = t & 127;
        sco[a][c] = coefs[a * 512 + b * 128 + c];
    }
    __syncthreads();
    const float* rp = RGB + (size_t)b * NC * HW;
    const float* tp = T + (size_t)b * NC * HW;
    f32x2 rv[16], tv[16];
    f32x2 df; df.x = 0.f; df.y = 0.f;
    #pragma unroll
    for (int ci = 0; ci < 16; ++ci) {
        int c = w * 16 + ci;
        size_t off = (size_t)c * HW + pix;
        rv[ci] = *(const f32x2*)(rp + off);
        tv[ci] = *(const f32x2*)(tp + off);
        float wrc = sco[2][c], wtc = sco[3][c];
        df.x += rv[ci].x * wrc - tv[ci].x * wtc;
        df.y += rv[ci].y * wrc - tv[ci].y * wtc;
    }
    __shared__ f32x2 sdf[8][64];
    sdf[w][lane] = df;
    __syncthreads();
    float sx = srb[0] - stb[0], sy = sx;
    #pragma unroll
    for (int ww = 0; ww < 8; ++ww) {
        f32x2 d = sdf[ww][lane];
        sx += d.x;
        sy += d.y;
    }
    float ax = sigmoidf_(sx), ay = sigmoidf_(sy);
    float* outR = out + (size_t)b * NC * HW;
    float* outT = out + (size_t)NB * NC * HW + (size_t)b * NC * HW;
    #pragma unroll
    for (int ci = 0; ci < 16; ++ci) {
        int c = w * 16 + ci;
        size_t off = (size_t)c * HW + pix;
        float arc = sco[0][c], atc = sco[1][c];
        f32x2 o1, o2;
        o1.x = rv[ci].x * arc * ax;         o1.y = rv[ci].y * arc * ay;
        o2.x = tv[ci].x * atc * (1.f - ax); o2.y = tv[ci].y * atc * (1.f - ay);
        __builtin_nontemporal_store(o1, (f32x2*)(outR + off));
        __builtin_nontemporal_store(o2, (f32x2*)(outT + off));
    }
}

extern "C" void kernel_launch(void* const* d_in, const int* in_sizes, int n_in,
                              void* d_out, int out_size, void* d_ws, size_t ws_size,
                              hipStream_t stream) {
    const float* RGB       = (const float*)d_in[0];
    const float* T         = (const float*)d_in[1];
    const float* fp_down_w = (const float*)d_in[2];
    const float* fp_down_b = (const float*)d_in[3];
    const float* fp_up_w   = (const float*)d_in[4];
    const float* fp_up_b   = (const float*)d_in[5];
    const float* dw_w      = (const float*)d_in[6];
    const float* dw_b      = (const float*)d_in[7];
    const float* ca_down_w = (const float*)d_in[8];
    const float* ca_down_b = (const float*)d_in[9];
    const float* ca_up_w   = (const float*)d_in[10];
    const float* ca_up_b   = (const float*)d_in[11];
    const float* sr_w      = (const float*)d_in[12];
    const float* sr_b      = (const float*)d_in[13];
    const float* st_w      = (const float*)d_in[14];
    const float* st_b      = (const float*)d_in[15];
    float* out = (float*)d_out;
    float* ws  = (float*)d_ws;

    // ws float layout (proven footprint):
    //   [0,1024)        means
    //   [1024,2048)     ynorm
    //   [2048,12288)    conv partial maxes
    //   [12288,14336)   coefs: alpha_r | alpha_t | wr | wt
    //   [14336,26880)   wpk: packed f16x2 conv weights [g][ky][oc][kx]
    unsigned* wpk = (unsigned*)(ws + 14336);
    mean_pack_kernel<<<1073, 256, 0, stream>>>(RGB, T, dw_w, ws, wpk);
    mlp_kernel<<<8, 256, 0, stream>>>(ws, fp_down_w, fp_down_b, fp_up_w, fp_up_b, ws + 1024);
    conv_max_kernel<<<5120, 256, 0, stream>>>(RGB, T, wpk, ws + 1024, ws + 2048);
    att_kernel<<<1, 256, 0, stream>>>(ws + 1024, ws + 2048, dw_b, ca_down_w, ca_down_b,
                                      ca_up_w, ca_up_b, sr_w, st_w, ws + 12288);
    fuse_kernel<<<dim3(200, 4), 512, 0, stream>>>(RGB, T, ws + 12288, sr_b, st_b, out);
}

// Round 17
// 127.922 us; speedup vs baseline: 1.0559x; 1.0478x over previous
//
#include <hip/hip_runtime.h>
#include <cfloat>
#include <cmath>

#define HW 25600      // 160*160
#define WIDTH 160
#define NB 4
#define NC 128

typedef float f32x2 __attribute__((ext_vector_type(2)));
typedef _Float16 h2 __attribute__((ext_vector_type(2)));

__device__ __forceinline__ float gelu_exact(float x) {
    return 0.5f * x * (1.f + erff(x * 0.70710678118654752f));
}
__device__ __forceinline__ float sigmoidf_(float x) {
    return 1.f / (1.f + expf(-x));
}

__device__ __forceinline__ unsigned pack_pkrtz(float a, float b) {
    return __builtin_bit_cast(unsigned, __builtin_amdgcn_cvt_pkrtz(a, b));
}
__device__ __forceinline__ h2 u2h(unsigned u) {
    return __builtin_bit_cast(h2, u);
}
__device__ __forceinline__ float h2sum(h2 h) {
    return (float)h[0] + (float)h[1];
}
__device__ __forceinline__ h2 fma2h(h2 a, h2 b, h2 c) {
    return __builtin_elementwise_fma(a, b, c);
}

// ---------------- K1: per-plane means + (merged) conv-weight pack ----------------
__global__ __launch_bounds__(256) void mean_pack_kernel(const float* __restrict__ RGB,
                                                        const float* __restrict__ T,
                                                        const float* __restrict__ dww,
                                                        float* __restrict__ means,
                                                        unsigned* __restrict__ wpk) {
    int p = blockIdx.x;
    if (p >= 1024) {
        int i = (p - 1024) * 256 + threadIdx.x;  // 128*98 = 12544
        if (i < 128 * 98) {
            int g = i / 98; int r = i - g * 98;
            int ky = r / 14; int r2 = r - ky * 14;
            int oc = r2 / 7; int kx = r2 - oc * 7;
            int o = 2 * g + oc;
            float wa = dww[(o * 2 + 0) * 49 + ky * 7 + kx];
            float wb = dww[(o * 2 + 1) * 49 + ky * 7 + kx];
            wpk[i] = pack_pkrtz(wa, wb);
        }
        return;
    }
    const float* src = (p < 512) ? (RGB + (size_t)p * HW)
                                 : (T + (size_t)(p - 512) * HW);
    const float4* s4 = (const float4*)src;
    float s = 0.f;
    for (int i = threadIdx.x; i < HW / 4; i += 256) {
        float4 v = s4[i];
        s += (v.x + v.y) + (v.z + v.w);
    }
    for (int off = 32; off; off >>= 1) s += __shfl_down(s, off);
    __shared__ float r[4];
    if ((threadIdx.x & 63) == 0) r[threadIdx.x >> 6] = s;
    __syncthreads();
    if (threadIdx.x == 0) means[p] = (r[0] + r[1] + r[2] + r[3]) * (1.f / (float)HW);
}

// ---------------- K2: feature-pool MLP + L2-normalize, per (tau,b) ----------------
__global__ __launch_bounds__(256) void mlp_kernel(const float* __restrict__ means,
                                                  const float* __restrict__ dww,
                                                  const float* __restrict__ dwb,
                                                  const float* __restrict__ uww,
                                                  const float* __restrict__ uwb,
                                                  float* __restrict__ ynorm) {
    int tb = blockIdx.x;  // tau*4 + b
    int t = threadIdx.x;
    __shared__ float sm[128];
    __shared__ float sh[256];
    __shared__ float zz[256];
    __shared__ float r4[4];
    if (t < 128) sm[t] = means[tb * 128 + t];
    __syncthreads();
    float a = dwb[t];
    const float* wrow = dww + t * 128;
    for (int c = 0; c < 128; ++c) a += wrow[c] * sm[c];
    sh[t] = gelu_exact(a);
    __syncthreads();
    int c = t & 127, half = t >> 7;
    float z = 0.f;
    const float* urow = uww + c * 256 + half * 128;
    const float* hh = sh + half * 128;
    for (int j = 0; j < 128; ++j) z += urow[j] * hh[j];
    zz[t] = z;
    __syncthreads();
    float y = 0.f;
    if (t < 128) y = zz[t] + zz[t + 128] + uwb[t];
    float p = y * y;
    for (int off = 32; off; off >>= 1) p += __shfl_down(p, off);
    if ((t & 63) == 0) r4[t >> 6] = p;
    __syncthreads();
    float nrm = sqrtf(r4[0] + r4[1] + r4[2] + r4[3]);
    if (t < 128) ynorm[tb * 128 + t] = y / nrm;
}

// ---------------- K3: gated grouped 7x7 conv + spatial max ----------------
// R17: staging strength-reduction (no div/mod in e-loop). MAC loop = R16 (passed).
#define TW2 166
#define THR 22
#define NYT 10
__global__ __launch_bounds__(256, 4) void conv_max_kernel(const float* __restrict__ RGB,
                                                          const float* __restrict__ T,
                                                          const unsigned* __restrict__ wpk,
                                                          const float* __restrict__ ynorm,
                                                          float* __restrict__ part) {
    // bijective XCD swizzle: 5120 blocks, 5120 % 8 == 0
    int orig = blockIdx.x;
    int wg = (orig & 7) * 640 + (orig >> 3);
    int b  = wg / 1280;
    int rr = wg - b * 1280;
    int g  = rr / NYT;
    int yt = rr - g * NYT;
    int t  = threadIdx.x;
    __shared__ unsigned tile[THR * TW2];   // 14.6 KB
    __shared__ float r0s[4], r1s[4];
    int ic0 = 2 * g;
    int c0 = ic0 & 127, c1 = (ic0 + 1) & 127;
    const float* base = (ic0 < 128) ? RGB : T;
    const float* plane0 = base + ((size_t)(b * 128 + c0)) * HW;
    const float* plane1 = base + ((size_t)(b * 128 + c1)) * HW;
    int i0 = b * 128 + c0, i1 = b * 128 + c1;
    int j0 = i0 & 3, k0 = i0 >> 2, j1 = i1 & 3, k1 = i1 >> 2;
    float gate0 = sigmoidf_(128.f * ynorm[j0 * 128 + j0] * ynorm[512 + j0 * 128 + k0]);
    float gate1 = sigmoidf_(128.f * ynorm[j1 * 128 + j1] * ynorm[512 + j1 * 128 + k1]);
    int y0 = yt * 16 - 3;
    {
        int row = t / TW2;
        int col = t - row * TW2;
        for (int e = t; e < THR * TW2; e += 256) {
            int gy = y0 + row, gx = col - 3;
            float v0 = 0.f, v1 = 0.f;
            if ((unsigned)gy < 160u && (unsigned)gx < 160u) {
                int off = gy * WIDTH + gx;
                v0 = plane0[off] * gate0;
                v1 = plane1[off] * gate1;
            }
            tile[e] = pack_pkrtz(v0, v1);
            col += 256 - TW2;
            ++row;
            if (col >= TW2) { col -= TW2; ++row; }
        }
    }
    __syncthreads();
    int xs = (t & 15) * 10;     // 40 B aligned -> uint2 ok
    int ys = t >> 4;            // 0..15
    h2 zzv = (h2)0;
    h2 A0 = zzv, A1 = zzv, A2 = zzv, A3 = zzv, A4 = zzv;
    h2 A5 = zzv, A6 = zzv, A7 = zzv, A8 = zzv, A9 = zzv;
    h2 B0 = zzv, B1 = zzv, B2 = zzv, B3 = zzv, B4 = zzv;
    h2 B5 = zzv, B6 = zzv, B7 = zzv, B8 = zzv, B9 = zzv;
    const unsigned* wgp = wpk + g * 98;   // block-uniform -> scalar loads
    #pragma unroll
    for (int ky = 0; ky < 7; ++ky) {
        unsigned wk[14];
        #pragma unroll
        for (int j = 0; j < 14; ++j) wk[j] = wgp[ky * 14 + j];
        const uint2* tr2 = (const uint2*)(tile + (ys + ky) * TW2 + xs);
        unsigned win[16];
        #pragma unroll
        for (int j = 0; j < 8; ++j) {
            uint2 p = tr2[j];
            win[2 * j] = p.x;
            win[2 * j + 1] = p.y;
        }
        #pragma unroll
        for (int kx = 0; kx < 7; ++kx) {
            h2 w0 = u2h(wk[kx]);
            h2 w1 = u2h(wk[7 + kx]);
            h2 v;
            v = u2h(win[kx + 0]); A0 = fma2h(w0, v, A0); B0 = fma2h(w1, v, B0);
            v = u2h(win[kx + 1]); A1 = fma2h(w0, v, A1); B1 = fma2h(w1, v, B1);
            v = u2h(win[kx + 2]); A2 = fma2h(w0, v, A2); B2 = fma2h(w1, v, B2);
            v = u2h(win[kx + 3]); A3 = fma2h(w0, v, A3); B3 = fma2h(w1, v, B3);
            v = u2h(win[kx + 4]); A4 = fma2h(w0, v, A4); B4 = fma2h(w1, v, B4);
            v = u2h(win[kx + 5]); A5 = fma2h(w0, v, A5); B5 = fma2h(w1, v, B5);
            v = u2h(win[kx + 6]); A6 = fma2h(w0, v, A6); B6 = fma2h(w1, v, B6);
            v = u2h(win[kx + 7]); A7 = fma2h(w0, v, A7); B7 = fma2h(w1, v, B7);
            v = u2h(win[kx + 8]); A8 = fma2h(w0, v, A8); B8 = fma2h(w1, v, B8);
            v = u2h(win[kx + 9]); A9 = fma2h(w0, v, A9); B9 = fma2h(w1, v, B9);
        }
    }
    float m0 = fmaxf(fmaxf(fmaxf(h2sum(A0), h2sum(A1)), fmaxf(h2sum(A2), h2sum(A3))),
                     fmaxf(fmaxf(h2sum(A4), h2sum(A5)),
                           fmaxf(fmaxf(h2sum(A6), h2sum(A7)), fmaxf(h2sum(A8), h2sum(A9)))));
    float m1 = fmaxf(fmaxf(fmaxf(h2sum(B0), h2sum(B1)), fmaxf(h2sum(B2), h2sum(B3))),
                     fmaxf(fmaxf(h2sum(B4), h2sum(B5)),
                           fmaxf(fmaxf(h2sum(B6), h2sum(B7)), fmaxf(h2sum(B8), h2sum(B9)))));
    for (int off = 32; off; off >>= 1) {
        m0 = fmaxf(m0, __shfl_down(m0, off));
        m1 = fmaxf(m1, __shfl_down(m1, off));
    }
    if ((t & 63) == 0) { r0s[t >> 6] = m0; r1s[t >> 6] = m1; }
    __syncthreads();
    if (t == 0) {
        m0 = fmaxf(fmaxf(r0s[0], r0s[1]), fmaxf(r0s[2], r0s[3]));
        m1 = fmaxf(fmaxf(r1s[0], r1s[1]), fmaxf(r1s[2], r1s[3]));
        int bb = ((b * 128 + g) * NYT + yt) * 2;
        part[bb] = m0;
        part[bb + 1] = m1;
    }
}

// ---------------- K4: fused channel-att + spatial-att fuse (att folded per-block) ----------------
// Each block recomputes its batch-b coefs from part/ynorm (~0.7us, L2-hot),
// removing the separate att launch + gap. Pixel phase identical to R16 (passed).
__global__ __launch_bounds__(512, 4) void fuse_att_kernel(const float* __restrict__ RGB,
                                                          const float* __restrict__ T,
                                                          const float* __restrict__ part,
                                                          const float* __restrict__ ynorm,
                                                          const float* __restrict__ dwb,
                                                          const float* __restrict__ cdw,
                                                          const float* __restrict__ cdb,
                                                          const float* __restrict__ cuw,
                                                          const float* __restrict__ cub,
                                                          const float* __restrict__ srw,
                                                          const float* __restrict__ stw,
                                                          const float* __restrict__ srb,
                                                          const float* __restrict__ stb,
                                                          float* __restrict__ out) {
    int b = blockIdx.y;
    int t = threadIdx.x;
    int w = t >> 6, lane = t & 63;
    int pix = blockIdx.x * 128 + lane * 2;
    __shared__ float smax[256];
    __shared__ float part_d[256];
    __shared__ float sh2[16];
    __shared__ float sfg[256];
    __shared__ float sco[4][128];
    // --- channel-att for this batch b (verbatim math from att_kernel) ---
    if (t < 256) {
        int o = t, gg = o >> 1, oc = o & 1;
        const float* pp = part + ((b * 128 + gg) * NYT) * 2 + oc;
        float m = pp[0];
        #pragma unroll
        for (int yt = 1; yt < NYT; ++yt) m = fmaxf(m, pp[yt * 2]);
        smax[o] = m + dwb[o];
    }
    __syncthreads();
    if (t < 256) {
        int j = t & 15, seg = t >> 4;   // 16 segments of 16 elements
        const float* wrow = cdw + j * 256 + seg * 16;
        const float* mx = smax + seg * 16;
        float a = 0.f;
        #pragma unroll
        for (int o = 0; o < 16; ++o) a += wrow[o] * mx[o];
        part_d[t] = a;
    }
    __syncthreads();
    if (t < 16) {
        float a = cdb[t];
        #pragma unroll
        for (int s = 0; s < 16; ++s) a += part_d[s * 16 + t];
        sh2[t] = gelu_exact(a);
    }
    __syncthreads();
    if (t < 256) {
        int o = t;
        float z = cub[o];
        const float* ur = cuw + o * 16;
        #pragma unroll
        for (int j = 0; j < 16; ++j) z += ur[j] * sh2[j];
        sfg[o] = sigmoidf_(z);
    }
    __syncthreads();
    if (t < 128) {
        int c = t;
        int idx = b * 128 + c;
        int kk = idx >> 2, j2 = idx & 3;
        float cg = sigmoidf_(128.f * ynorm[j2 * 128 + j2] * ynorm[512 + j2 * 128 + kk]);
        float ar = cg * sfg[c] + 1.f - cg;
        float at = cg * sfg[128 + c] + 1.f - cg;
        sco[0][c] = ar;
        sco[1][c] = at;
        sco[2][c] = ar * srw[c];
        sco[3][c] = at * stw[c];
    }
    __syncthreads();
    // --- pixel phase (R16-proven single pass) ---
    const float* rp = RGB + (size_t)b * NC * HW;
    const float* tp = T + (size_t)b * NC * HW;
    f32x2 rv[16], tv[16];
    f32x2 df; df.x = 0.f; df.y = 0.f;
    #pragma unroll
    for (int ci = 0; ci < 16; ++ci) {
        int c = w * 16 + ci;
        size_t off = (size_t)c * HW + pix;
        rv[ci] = *(const f32x2*)(rp + off);
        tv[ci] = *(const f32x2*)(tp + off);
        float wrc = sco[2][c], wtc = sco[3][c];
        df.x += rv[ci].x * wrc - tv[ci].x * wtc;
        df.y += rv[ci].y * wrc - tv[ci].y * wtc;
    }
    __shared__ f32x2 sdf[8][64];
    sdf[w][lane] = df;
    __syncthreads();
    float sx = srb[0] - stb[0], sy = sx;
    #pragma unroll
    for (int ww = 0; ww < 8; ++ww) {
        f32x2 d = sdf[ww][lane];
        sx += d.x;
        sy += d.y;
    }
    float ax = sigmoidf_(sx), ay = sigmoidf_(sy);
    float* outR = out + (size_t)b * NC * HW;
    float* outT = out + (size_t)NB * NC * HW + (size_t)b * NC * HW;
    #pragma unroll
    for (int ci = 0; ci < 16; ++ci) {
        int c = w * 16 + ci;
        size_t off = (size_t)c * HW + pix;
        float arc = sco[0][c], atc = sco[1][c];
        f32x2 o1, o2;
        o1.x = rv[ci].x * arc * ax;         o1.y = rv[ci].y * arc * ay;
        o2.x = tv[ci].x * atc * (1.f - ax); o2.y = tv[ci].y * atc * (1.f - ay);
        __builtin_nontemporal_store(o1, (f32x2*)(outR + off));
        __builtin_nontemporal_store(o2, (f32x2*)(outT + off));
    }
}

extern "C" void kernel_launch(void* const* d_in, const int* in_sizes, int n_in,
                              void* d_out, int out_size, void* d_ws, size_t ws_size,
                              hipStream_t stream) {
    const float* RGB       = (const float*)d_in[0];
    const float* T         = (const float*)d_in[1];
    const float* fp_down_w = (const float*)d_in[2];
    const float* fp_down_b = (const float*)d_in[3];
    const float* fp_up_w   = (const float*)d_in[4];
    const float* fp_up_b   = (const float*)d_in[5];
    const float* dw_w      = (const float*)d_in[6];
    const float* dw_b      = (const float*)d_in[7];
    const float* ca_down_w = (const float*)d_in[8];
    const float* ca_down_b = (const float*)d_in[9];
    const float* ca_up_w   = (const float*)d_in[10];
    const float* ca_up_b   = (const float*)d_in[11];
    const float* sr_w      = (const float*)d_in[12];
    const float* sr_b      = (const float*)d_in[13];
    const float* st_w      = (const float*)d_in[14];
    const float* st_b      = (const float*)d_in[15];
    float* out = (float*)d_out;
    float* ws  = (float*)d_ws;

    // ws float layout (proven footprint):
    //   [0,1024)        means
    //   [1024,2048)     ynorm
    //   [2048,12288)    conv partial maxes
    //   [14336,26880)   wpk: packed f16x2 conv weights [g][ky][oc][kx]
    unsigned* wpk = (unsigned*)(ws + 14336);
    mean_pack_kernel<<<1073, 256, 0, stream>>>(RGB, T, dw_w, ws, wpk);
    mlp_kernel<<<8, 256, 0, stream>>>(ws, fp_down_w, fp_down_b, fp_up_w, fp_up_b, ws + 1024);
    conv_max_kernel<<<5120, 256, 0, stream>>>(RGB, T, wpk, ws + 1024, ws + 2048);
    fuse_att_kernel<<<dim3(200, 4), 512, 0, stream>>>(RGB, T, ws + 2048, ws + 1024,
                                                      dw_b, ca_down_w, ca_down_b,
                                                      ca_up_w, ca_up_b, sr_w, st_w,
                                                      sr_b, st_b, out);
}